// Round 7
// baseline (389.028 us; speedup 1.0000x reference)
//
#include <hip/hip_runtime.h>
#include <hip/hip_bf16.h>

typedef __bf16 bf16x8 __attribute__((ext_vector_type(8)));
typedef float  f32x4  __attribute__((ext_vector_type(4)));

#define B_ROWS 65536
#define KC1 25           // 800/32 (K padded 784 -> 800, pad rows are zero in W1eff)
#define KC2 8
#define KC3 4
#define H1S 264          // h1 LDS stride (256+8 pad)
#define H2S 136          // h2 LDS stride (128+8 pad)

#define W1E_ELEMS (800*256)
#define W2B_ELEMS (256*128)
#define W3B_ELEMS (128*16)

// ---- pack kernel: builds W1eff (conv folded into w1) + w2b + w3b ----------
// All in bf16 MFMA-B layout [kc][n][ki(32)]: lane's 8 k-values contiguous.
// W1eff[pi*28+pj][n] = sum_{di,dj in [0,3)} [0<=pi-di<26][0<=pj-dj<26]
//                      * cw[di*3+dj] * w1[((pi-di)*26+(pj-dj))*256 + n]
__global__ void pack_weights(const float* __restrict__ cw,
                             const float* __restrict__ w1,
                             const float* __restrict__ w2,
                             const float* __restrict__ w3,
                             __hip_bfloat16* __restrict__ w1e,
                             __hip_bfloat16* __restrict__ w2b,
                             __hip_bfloat16* __restrict__ w3b) {
    int idx = blockIdx.x * 256 + threadIdx.x;
    if (idx < W1E_ELEMS) {
        int ki = idx & 31, t = idx >> 5;
        int n = t & 255, kc = t >> 8;
        int k = kc * 32 + ki;
        float acc = 0.0f;
        if (k < 784) {
            int pi = k / 28, pj = k - pi * 28;
            #pragma unroll
            for (int di = 0; di < 3; di++) {
                int i = pi - di;
                if (i < 0 || i >= 26) continue;
                #pragma unroll
                for (int dj = 0; dj < 3; dj++) {
                    int j = pj - dj;
                    if (j < 0 || j >= 26) continue;
                    acc += cw[di * 3 + dj] * w1[(i * 26 + j) * 256 + n];
                }
            }
        }
        w1e[idx] = __float2bfloat16(acc);
    } else if (idx < W1E_ELEMS + W2B_ELEMS) {
        int j = idx - W1E_ELEMS;
        int ki = j & 31, t = j >> 5;
        int n = t & 127, kc = t >> 7;
        w2b[j] = __float2bfloat16(w2[(kc * 32 + ki) * 128 + n]);
    } else if (idx < W1E_ELEMS + W2B_ELEMS + W3B_ELEMS) {
        int j = idx - W1E_ELEMS - W2B_ELEMS;
        int ki = j & 31, t = j >> 5;
        int n = t & 15, kc = t >> 4;
        float v = (n < 10) ? w3[(kc * 32 + ki) * 10 + n] : 0.0f;
        w3b[j] = __float2bfloat16(v);
    }
}

// convert 8 consecutive fp32 (two float4) to a bf16x8 A-fragment chunk
__device__ __forceinline__ bf16x8 cvt8(float4 u0, float4 u1) {
    bf16x8 a;
    a[0] = (__bf16)u0.x; a[1] = (__bf16)u0.y; a[2] = (__bf16)u0.z; a[3] = (__bf16)u0.w;
    a[4] = (__bf16)u1.x; a[5] = (__bf16)u1.y; a[6] = (__bf16)u1.z; a[7] = (__bf16)u1.w;
    return a;
}

// ---- model kernel: x[B,784] fp32 -> out[B,10] -----------------------------
// GEMM1: A read directly from x (rows contiguous; lane chunk = 32B aligned),
// cvt fp32->bf16 in-register. K padded to 800; k>=784 weights are ZERO so
// A-values there are don't-care (address clamped in-bounds).
// M=32/block, 256 thr. LDS 25.6 KB -> 6 blocks/CU by LDS; VGPR cap 128 (4/EU).
__global__ __launch_bounds__(256, 4)
void model_kernel(const float* __restrict__ x,
                  const __hip_bfloat16* __restrict__ w1e, const float* __restrict__ b1,
                  const __hip_bfloat16* __restrict__ w2b, const float* __restrict__ b2,
                  const __hip_bfloat16* __restrict__ w3b, const float* __restrict__ b3,
                  float* __restrict__ out) {
    __shared__ __align__(16) __hip_bfloat16 h1s[32 * H1S];
    __shared__ __align__(16) __hip_bfloat16 h2s[32 * H2S];

    const int tid  = threadIdx.x;
    const int wave = tid >> 6;
    const int lane = tid & 63;
    const int l15  = lane & 15;
    const int g    = lane >> 4;
    const int r0   = blockIdx.x * 32;

    // ---- GEMM1: h1 = relu(x @ W1eff + b1), M=32 N=256 K=800 ----
    {
        // A row pointers for the two 16-row m-tiles
        const float* a0p = x + (size_t)(r0 + l15) * 784;
        const float* a1p = x + (size_t)(r0 + 16 + l15) * 784;
        const int nb = wave * 64;
        const __hip_bfloat16* bbase = w1e + ((size_t)(nb + l15) * 32 + g * 8);

        f32x4 acc[2][4];
        #pragma unroll
        for (int mt = 0; mt < 2; mt++)
            #pragma unroll
            for (int nt = 0; nt < 4; nt++)
                acc[mt][nt] = (f32x4){0.f, 0.f, 0.f, 0.f};

        // col for chunk kc: kc*32 + g*8, clamped in-bounds for the zero-weight
        // tail (kc==24, g>=2 -> k>=784: W1eff rows are zero, value don't-care).
        int col0 = g * 8;                      // kc = 0 (always < 784)
        bf16x8 bcur[4], acur[2];
        {
            float4 u0 = *(const float4*)(a0p + col0);
            float4 u1 = *(const float4*)(a0p + col0 + 4);
            float4 v0 = *(const float4*)(a1p + col0);
            float4 v1 = *(const float4*)(a1p + col0 + 4);
            acur[0] = cvt8(u0, u1);
            acur[1] = cvt8(v0, v1);
        }
        #pragma unroll
        for (int nt = 0; nt < 4; nt++)
            bcur[nt] = *(const bf16x8*)(bbase + nt * 512);

        for (int kc = 0; kc < KC1; kc++) {
            bf16x8 bnext[4], anext[2];
            if (kc + 1 < KC1) {
                int col = (kc + 1) * 32 + g * 8;
                if (col > 776) col = 776;      // clamp: zero-weight tail
                float4 u0 = *(const float4*)(a0p + col);
                float4 u1 = *(const float4*)(a0p + col + 4);
                float4 v0 = *(const float4*)(a1p + col);
                float4 v1 = *(const float4*)(a1p + col + 4);
                const __hip_bfloat16* bp = bbase + (size_t)(kc + 1) * 8192;
                #pragma unroll
                for (int nt = 0; nt < 4; nt++)
                    bnext[nt] = *(const bf16x8*)(bp + nt * 512);
                anext[0] = cvt8(u0, u1);
                anext[1] = cvt8(v0, v1);
            }
            #pragma unroll
            for (int mt = 0; mt < 2; mt++)
                #pragma unroll
                for (int nt = 0; nt < 4; nt++)
                    acc[mt][nt] = __builtin_amdgcn_mfma_f32_16x16x32_bf16(
                        acur[mt], bcur[nt], acc[mt][nt], 0, 0, 0);
            if (kc + 1 < KC1) {
                #pragma unroll
                for (int nt = 0; nt < 4; nt++) bcur[nt] = bnext[nt];
                acur[0] = anext[0];
                acur[1] = anext[1];
            }
        }
        #pragma unroll
        for (int nt = 0; nt < 4; nt++) {
            const int n = nb + nt * 16 + l15;
            const float bias = b1[n];
            #pragma unroll
            for (int mt = 0; mt < 2; mt++) {
                #pragma unroll
                for (int q = 0; q < 4; q++) {
                    const int row = mt * 16 + g * 4 + q;   // col=lane&15, row=(lane>>4)*4+q
                    float v = acc[mt][nt][q] + bias;
                    h1s[row * H1S + n] = __float2bfloat16(fmaxf(v, 0.0f));
                }
            }
        }
    }
    __syncthreads();

    // ---- GEMM2: h2 = relu(h1 @ w2 + b2), M=32 N=128 K=256 ----
    {
        f32x4 acc[2][2];
        #pragma unroll
        for (int mt = 0; mt < 2; mt++)
            #pragma unroll
            for (int nt = 0; nt < 2; nt++)
                acc[mt][nt] = (f32x4){0.f, 0.f, 0.f, 0.f};
        const int nb = wave * 32;
        #pragma unroll
        for (int kc = 0; kc < KC2; kc++) {
            bf16x8 a[2], b[2];
            #pragma unroll
            for (int mt = 0; mt < 2; mt++)
                a[mt] = *(const bf16x8*)(h1s + (mt * 16 + l15) * H1S + kc * 32 + g * 8);
            #pragma unroll
            for (int nt = 0; nt < 2; nt++)
                b[nt] = *(const bf16x8*)(w2b + (((size_t)kc * 128 + nb + nt * 16 + l15) * 32 + g * 8));
            #pragma unroll
            for (int mt = 0; mt < 2; mt++)
                #pragma unroll
                for (int nt = 0; nt < 2; nt++)
                    acc[mt][nt] = __builtin_amdgcn_mfma_f32_16x16x32_bf16(
                        a[mt], b[nt], acc[mt][nt], 0, 0, 0);
        }
        #pragma unroll
        for (int nt = 0; nt < 2; nt++) {
            const int n = nb + nt * 16 + l15;
            const float bias = b2[n];
            #pragma unroll
            for (int mt = 0; mt < 2; mt++) {
                #pragma unroll
                for (int q = 0; q < 4; q++) {
                    const int row = mt * 16 + g * 4 + q;
                    float v = acc[mt][nt][q] + bias;
                    h2s[row * H2S + n] = __float2bfloat16(fmaxf(v, 0.0f));
                }
            }
        }
    }
    __syncthreads();

    // ---- GEMM3: out = h2 @ w3 + b3, M=32 N=16(10) K=128 ----
    if (wave < 2) {
        f32x4 acc3 = (f32x4){0.f, 0.f, 0.f, 0.f};
        #pragma unroll
        for (int kc = 0; kc < KC3; kc++) {
            bf16x8 a = *(const bf16x8*)(h2s + (wave * 16 + l15) * H2S + kc * 32 + g * 8);
            bf16x8 b = *(const bf16x8*)(w3b + (((size_t)kc * 16 + l15) * 32 + g * 8));
            acc3 = __builtin_amdgcn_mfma_f32_16x16x32_bf16(a, b, acc3, 0, 0, 0);
        }
        if (l15 < 10) {
            const float bias = b3[l15];
            #pragma unroll
            for (int q = 0; q < 4; q++) {
                const int row = wave * 16 + g * 4 + q;
                out[(size_t)(r0 + row) * 10 + l15] = acc3[q] + bias;
            }
        }
    }
}

extern "C" void kernel_launch(void* const* d_in, const int* in_sizes, int n_in,
                              void* d_out, int out_size, void* d_ws, size_t ws_size,
                              hipStream_t stream) {
    const float* x  = (const float*)d_in[0];
    const float* cw = (const float*)d_in[1];
    const float* w1 = (const float*)d_in[2];
    const float* b1 = (const float*)d_in[3];
    const float* w2 = (const float*)d_in[4];
    const float* b2 = (const float*)d_in[5];
    const float* w3 = (const float*)d_in[6];
    const float* b3 = (const float*)d_in[7];
    float* out = (float*)d_out;

    __hip_bfloat16* w1e = (__hip_bfloat16*)d_ws;
    __hip_bfloat16* w2b = w1e + W1E_ELEMS;
    __hip_bfloat16* w3b = w2b + W2B_ELEMS;

    const int pack_total = W1E_ELEMS + W2B_ELEMS + W3B_ELEMS;  // 239616
    pack_weights<<<(pack_total + 255) / 256, 256, 0, stream>>>(cw, w1, w2, w3, w1e, w2b, w3b);
    model_kernel<<<B_ROWS / 32, 256, 0, stream>>>(x, w1e, b1, w2b, b2, w3b, b3, out);
}